// Round 2
// baseline (184.873 us; speedup 1.0000x reference)
//
#include <hip/hip_runtime.h>

// VisualRetina: strided 32x32 downsample -> Z-order -> per-16-chunk cubic LS
// fit -> [4 coeffs + sigma] channel-mean.
//
// Round 2 restructure: one block per image (256 blocks x 192 threads,
// 3 waves/CU). Wave c stages channel c's 32x32 strided grid into LDS with
// coalesced-order loads (16 independent loads/thread). Then wave 0's 64
// lanes each compute one Z-order token from LDS. Math identical to the
// verified round-1 kernel (analytic parity-decoupled LS solve).

#define BATCH 256
#define NCHUNK 64
#define HW 224

__global__ __launch_bounds__(192) void retina_kernel(const float* __restrict__ x,
                                                     float* __restrict__ out) {
    __shared__ float g[3][1024];   // [channel][y*32+x] downsampled grid

    int b = blockIdx.x;
    int j = threadIdx.x;      // 0..191
    int c = j >> 6;           // wave index == channel
    int l = j & 63;           // lane

    const float* __restrict__ xc = x + ((size_t)b * 3 + c) * (HW * HW);

    // ---- load phase: 16 independent strided loads per thread ----
#pragma unroll
    for (int i = 0; i < 16; ++i) {
        int e = (i << 6) + l;        // element 0..1023, lane-contiguous
        int y = e >> 5;              // grid row 0..31
        int xg = e & 31;             // grid col 0..31
        g[c][e] = xc[(7 * y) * HW + 7 * xg];
    }
    __syncthreads();

    // ---- compute phase: wave 0, one token per lane ----
    if (j < 64) {
        int n = j;
        // deinterleave chunk index: even bits -> xh, odd bits -> yh
        int xh = (n & 1) | ((n >> 1) & 2) | ((n >> 2) & 4);
        int yh = ((n >> 1) & 1) | ((n >> 2) & 2) | ((n >> 3) & 4);

        float s0[3] = {0.f, 0.f, 0.f};  // sum y
        float s1[3] = {0.f, 0.f, 0.f};  // sum t y
        float s2[3] = {0.f, 0.f, 0.f};  // sum t^2 y
        float s3[3] = {0.f, 0.f, 0.f};  // sum t^3 y
        float sq[3] = {0.f, 0.f, 0.f};  // sum y^2

#pragma unroll
        for (int t = 0; t < 16; ++t) {
            int dx = (t & 1) | ((t >> 1) & 2);        // bits 0,2
            int dy = ((t >> 1) & 1) | ((t >> 2) & 2); // bits 1,3
            int idx = (4 * yh + dy) * 32 + (4 * xh + dx);
            float tt = -1.0f + (2.0f / 15.0f) * (float)t;
            float t2 = tt * tt;
            float t3 = t2 * tt;
#pragma unroll
            for (int cc = 0; cc < 3; ++cc) {
                float v = g[cc][idx];
                s0[cc] += v;
                s1[cc] += tt * v;
                s2[cc] += t2 * v;
                s3[cc] += t3 * v;
                sq[cc] += v * v;
            }
        }

        const float S0f = 16.0f;
        const float S2f = 1360.0f / 225.0f;          // sum t^2
        const float S4f = 206992.0f / 50625.0f;      // sum t^4
        const float S6f = 37308880.0f / 11390625.0f; // sum t^6
        const float inv_det_odd  = 1.0f / (S6f * S2f - S4f * S4f);
        const float inv_det_even = 1.0f / (S4f * S0f - S2f * S2f);

        float m0 = 0.f, m1 = 0.f, m2 = 0.f, m3 = 0.f, ms = 0.f;
#pragma unroll
        for (int cc = 0; cc < 3; ++cc) {
            float a_cube = (S2f * s3[cc] - S4f * s1[cc]) * inv_det_odd;
            float a_lin  = (S6f * s1[cc] - S4f * s3[cc]) * inv_det_odd;
            float a_quad = (S0f * s2[cc] - S2f * s0[cc]) * inv_det_even;
            float a_cons = (S4f * s0[cc] - S2f * s2[cc]) * inv_det_even;
            float ss = sq[cc] - (a_cube * s3[cc] + a_quad * s2[cc] +
                                 a_lin * s1[cc] + a_cons * s0[cc]);
            float sig = sqrtf(fmaxf(ss, 0.0f) * (1.0f / 16.0f));
            m0 += a_cube; m1 += a_quad; m2 += a_lin; m3 += a_cons; ms += sig;
        }

        float* o = out + ((size_t)b * NCHUNK + n) * 5;
        const float third = 1.0f / 3.0f;
        o[0] = m0 * third;
        o[1] = m1 * third;
        o[2] = m2 * third;
        o[3] = m3 * third;
        o[4] = ms * third;
    }
}

extern "C" void kernel_launch(void* const* d_in, const int* in_sizes, int n_in,
                              void* d_out, int out_size, void* d_ws, size_t ws_size,
                              hipStream_t stream) {
    const float* x = (const float*)d_in[0];
    float* out = (float*)d_out;
    retina_kernel<<<BATCH, 192, 0, stream>>>(x, out);
}